// Round 7
// baseline (150.375 us; speedup 1.0000x reference)
//
#include <hip/hip_runtime.h>
#include <hip/hip_bf16.h>

typedef __attribute__((ext_vector_type(8))) short bf16x8;
typedef __attribute__((ext_vector_type(4))) short s16x4;
typedef __attribute__((ext_vector_type(4))) float f32x4;

__device__ __forceinline__ short f2b(float f) {
    __hip_bfloat16 h = __float2bfloat16(f);   // RNE
    return __builtin_bit_cast(short, h);
}

// Kernel 1: x f32 -> bf16, and y2 = 2*(x @ A^T) as bf16.
__global__ void prep_kernel(const float* __restrict__ x,
                            const float* __restrict__ A,
                            ushort* __restrict__ xb,     // [64][4096] bf16
                            ushort* __restrict__ yb) {   // [64][64] bf16
    const int tid = threadIdx.x, bid = blockIdx.x;

    const int gid = bid * 256 + tid;
    if (gid < 65536) {
        float4 v = ((const float4*)x)[gid];
        ushort4 s;
        s.x = (ushort)f2b(v.x); s.y = (ushort)f2b(v.y);
        s.z = (ushort)f2b(v.z); s.w = (ushort)f2b(v.w);
        ((ushort4*)xb)[gid] = s;
    }

    const int wave = tid >> 6, lane = tid & 63;
    const int idx = bid * 4 + wave;          // 0..4095
    const int t = idx >> 6, r = idx & 63;
    const float4* xr = (const float4*)(x + (size_t)t * 4096);
    const float4* ar = (const float4*)(A + (size_t)r * 4096);
    float s = 0.f;
    #pragma unroll
    for (int i = 0; i < 16; ++i) {
        float4 a = xr[i * 64 + lane];
        float4 b = ar[i * 64 + lane];
        s += a.x * b.x + a.y * b.y + a.z * b.z + a.w * b.w;
    }
    #pragma unroll
    for (int off = 32; off; off >>= 1) s += __shfl_xor(s, off, 64);
    if (lane == 0) yb[idx] = (ushort)f2b(2.0f * s);
}

// Kernel 2: out[64][16384] = x@W^T + y2@B^T.
// 2048 blocks x 256 threads, 2 blocks/CU (64 KB LDS each).
// Block owns 8 W-rows = ONE CONTIGUOUS 128 KB panel, read STRICTLY LINEARLY
// (fill-kernel pattern: f32x4 at panel+it*256+tid) -> cvt bf16 -> LDS once ->
// single __syncthreads -> 128 barrier-free MFMA K-steps from LDS.
// Duty cycle comes from 2 independent blocks/CU overlapping load vs compute,
// not from intra-block scheduling (R2/R5/R6 showed those are null/negative).
// LDS layout: chunk (s, slot) -> byte s*512 + ((r^s)&7)*64 + inbyte.
// Both write pattern (per-wave 8 s-values alternating slot parity) and read
// pattern (8 rows x 4 kg) are uniform 4-pass over the 128 B bank period =
// the 512B/128B structural minimum (conflict-optimal).
__global__ void __launch_bounds__(256, 2)
lora_gemm(const float* __restrict__ W,      // [16384][4096]
          const float* __restrict__ Bm,     // [16384][64]
          const ushort* __restrict__ xb,    // [64][4096] bf16
          const ushort* __restrict__ yb,    // [64][64] bf16
          float* __restrict__ out) {        // [64][16384]
    __shared__ char lds[128 * 512];         // 64 KB = 8 rows x 4096 bf16

    const int tid  = threadIdx.x;
    const int w    = tid >> 6;              // wave -> token group
    const int lane = tid & 63;
    const int c    = lane & 15;             // A-row (token) / D-col index
    const int kg   = lane >> 4;             // k-group, offset kg*8
    const int j0   = blockIdx.x << 3;       // 8 output cols per block

    // ---- load phase: linear stream of the 128 KB panel, 2-bank pipeline ----
    const f32x4* panel = (const f32x4*)(W + (size_t)j0 * 4096);
    f32x4 stA[8], stB[8];

    #define LOADB(st, b)                                                   \
        { _Pragma("unroll")                                                \
          for (int i = 0; i < 8; ++i)                                      \
              st[i] = panel[((b) * 8 + i) * 256 + tid]; }

    #define WRITEB(st, b)                                                  \
        { _Pragma("unroll")                                                \
          for (int i = 0; i < 8; ++i) {                                    \
              const int it = (b) * 8 + i;                                  \
              const int r_ = it >> 2;                                      \
              const int s_ = (it & 3) * 32 + (tid >> 3);                   \
              s16x4 p;                                                     \
              p[0] = f2b(st[i][0]); p[1] = f2b(st[i][1]);                  \
              p[2] = f2b(st[i][2]); p[3] = f2b(st[i][3]);                  \
              *(s16x4*)(&lds[s_ * 512 + ((r_ ^ s_) & 7) * 64               \
                             + (tid & 7) * 8]) = p;                        \
          } }

    LOADB(stA, 0);
    LOADB(stB, 1);
    WRITEB(stA, 0);
    LOADB(stA, 2);
    WRITEB(stB, 1);
    LOADB(stB, 3);
    WRITEB(stA, 2);
    WRITEB(stB, 3);

    #undef LOADB
    #undef WRITEB

    __syncthreads();                         // only barrier in the kernel

    // ---- compute phase: 128 K-steps from LDS, zero barriers ----
    const ushort* xrow = xb + (size_t)(w * 16 + c) * 4096 + kg * 8;
    const int rr = c & 7;                    // cols >=8 duplicate 0..7 (unstored)

    f32x4 accA = {0.f, 0.f, 0.f, 0.f};
    f32x4 accB = {0.f, 0.f, 0.f, 0.f};

    #pragma unroll 8
    for (int s = 0; s < 128; s += 2) {
        bf16x8 b0 = *(const bf16x8*)(&lds[s * 512 + ((rr ^ s) & 7) * 64 + kg * 16]);
        bf16x8 a0 = *(const bf16x8*)(xrow + (size_t)s * 32);
        accA = __builtin_amdgcn_mfma_f32_16x16x32_bf16(a0, b0, accA, 0, 0, 0);
        bf16x8 b1 = *(const bf16x8*)(&lds[(s + 1) * 512 + ((rr ^ (s + 1)) & 7) * 64 + kg * 16]);
        bf16x8 a1 = *(const bf16x8*)(xrow + (size_t)(s + 1) * 32);
        accB = __builtin_amdgcn_mfma_f32_16x16x32_bf16(a1, b1, accB, 0, 0, 0);
    }

    // lora tail: 2 K-steps over r=64 with B matrix and y2 (into accA)
    {
        const float*  br = Bm + (size_t)(j0 + rr) * 64 + kg * 8;
        const ushort* y0 = yb + (size_t)(w * 16 + c) * 64 + kg * 8;
        #pragma unroll
        for (int k = 0; k < 64; k += 32) {
            f32x4 w0 = *(const f32x4*)(br + k);
            f32x4 w1 = *(const f32x4*)(br + k + 4);
            bf16x8 bb;
            bb[0] = f2b(w0[0]); bb[1] = f2b(w0[1]);
            bb[2] = f2b(w0[2]); bb[3] = f2b(w0[3]);
            bb[4] = f2b(w1[0]); bb[5] = f2b(w1[1]);
            bb[6] = f2b(w1[2]); bb[7] = f2b(w1[3]);
            bf16x8 aa = *(const bf16x8*)(y0 + k);
            accA = __builtin_amdgcn_mfma_f32_16x16x32_bf16(aa, bb, accA, 0, 0, 0);
        }
    }

    // store: token row = w*16 + kg*4 + r, col = j0 + c  (only c < 8 valid)
    if (c < 8) {
        float* op = out + j0 + c;
        #pragma unroll
        for (int r = 0; r < 4; ++r)
            op[(size_t)(w * 16 + kg * 4 + r) * 16384] = accA[r] + accB[r];
    }
}

extern "C" void kernel_launch(void* const* d_in, const int* in_sizes, int n_in,
                              void* d_out, int out_size, void* d_ws, size_t ws_size,
                              hipStream_t stream) {
    const float* x  = (const float*)d_in[0];
    const float* W  = (const float*)d_in[1];
    const float* A  = (const float*)d_in[2];
    const float* Bm = (const float*)d_in[3];
    float* out = (float*)d_out;

    ushort* xb = (ushort*)d_ws;                          // 64*4096*2 = 524288 B
    ushort* yb = (ushort*)((char*)d_ws + 524288);        // 64*64*2   = 8192 B

    prep_kernel<<<1024, 256, 0, stream>>>(x, A, xb, yb);
    lora_gemm<<<2048, 256, 0, stream>>>(W, Bm, xb, yb, out);
}

// Round 8
// 125.902 us; speedup vs baseline: 1.1944x; 1.1944x over previous
//
#include <hip/hip_runtime.h>
#include <hip/hip_bf16.h>

typedef __attribute__((ext_vector_type(8))) short bf16x8;
typedef __attribute__((ext_vector_type(4))) float f32x4;

__device__ __forceinline__ short f2b(float f) {
    __hip_bfloat16 h = __float2bfloat16(f);   // RNE
    return __builtin_bit_cast(short, h);
}

// Kernel 1: x f32 -> bf16, and y2 = 2*(x @ A^T) as bf16.
__global__ void prep_kernel(const float* __restrict__ x,
                            const float* __restrict__ A,
                            ushort* __restrict__ xb,     // [64][4096] bf16
                            ushort* __restrict__ yb) {   // [64][64] bf16
    const int tid = threadIdx.x, bid = blockIdx.x;

    const int gid = bid * 256 + tid;
    if (gid < 65536) {
        float4 v = ((const float4*)x)[gid];
        ushort4 s;
        s.x = (ushort)f2b(v.x); s.y = (ushort)f2b(v.y);
        s.z = (ushort)f2b(v.z); s.w = (ushort)f2b(v.w);
        ((ushort4*)xb)[gid] = s;
    }

    const int wave = tid >> 6, lane = tid & 63;
    const int idx = bid * 4 + wave;          // 0..4095
    const int t = idx >> 6, r = idx & 63;
    const float4* xr = (const float4*)(x + (size_t)t * 4096);
    const float4* ar = (const float4*)(A + (size_t)r * 4096);
    float s = 0.f;
    #pragma unroll
    for (int i = 0; i < 16; ++i) {
        float4 a = xr[i * 64 + lane];
        float4 b = ar[i * 64 + lane];
        s += a.x * b.x + a.y * b.y + a.z * b.z + a.w * b.w;
    }
    #pragma unroll
    for (int off = 32; off; off >>= 1) s += __shfl_xor(s, off, 64);
    if (lane == 0) yb[idx] = (ushort)f2b(2.0f * s);
}

// Kernel 2: out[64][16384] = x@W^T + y2@B^T.
// 1024 blocks x 64 threads (1 wave). Wave owns 16 cols x ALL 64 tokens.
// NO LDS, NO barriers, NO K-split. W is the only long-latency vmem stream;
// x-frags are prefetched distance-1-tile into two NAMED register banks
// (XA/XB, static indices only), so no vmcnt wait ever empties the W pipe:
// issue order ... XA(t), W(t,*), XB(t+1), W(t+1,*) ... keeps next-tile loads
// outstanding behind every wait (vmcnt retires in order; mixing fast x-loads
// into the stream was collapsing outstanding-reads to ~0 every tile in
// R1/R3/R5 -> the occupancy-invariant 3.2 TB/s wall).
__global__ void __launch_bounds__(64, 2)
lora_gemm(const float* __restrict__ W,      // [16384][4096]
          const float* __restrict__ Bm,     // [16384][64]
          const ushort* __restrict__ xb,    // [64][4096] bf16
          const ushort* __restrict__ yb,    // [64][64] bf16
          float* __restrict__ out) {        // [64][16384]
    const int lane = threadIdx.x;
    const int c    = lane & 15;              // col within 16-col panel / token row
    const int kg   = lane >> 4;              // k-group, offset kg*8
    const int j0   = blockIdx.x << 4;

    const float* wr = W + (size_t)(j0 + c) * 4096 + kg * 8;
    const ushort* xp[4] = {
        xb + (size_t)( 0 + c) * 4096 + kg * 8,
        xb + (size_t)(16 + c) * 4096 + kg * 8,
        xb + (size_t)(32 + c) * 4096 + kg * 8,
        xb + (size_t)(48 + c) * 4096 + kg * 8,
    };

    bf16x8 XA[4][4], XB[4][4];               // two x prefetch banks (static idx)
    f32x4 acc[4];
    #pragma unroll
    for (int tg = 0; tg < 4; ++tg) acc[tg] = f32x4{0.f, 0.f, 0.f, 0.f};

    // tile = 128 k-elems = 4 k-steps of 32
    #define LOADX(XF, t)                                                    \
        { _Pragma("unroll")                                                 \
          for (int tg = 0; tg < 4; ++tg) {                                  \
              _Pragma("unroll")                                             \
              for (int s = 0; s < 4; ++s)                                   \
                  XF[tg][s] = *(const bf16x8*)(xp[tg] + (t) * 128 + s * 32);\
          } }

    #define COMPT(XF, t)                                                    \
        { _Pragma("unroll")                                                 \
          for (int s = 0; s < 4; ++s) {                                     \
              const float* wk = wr + (t) * 128 + s * 32;                    \
              f32x4 w0 = *(const f32x4*)(wk);                               \
              f32x4 w1 = *(const f32x4*)(wk + 4);                           \
              bf16x8 bb;                                                    \
              bb[0] = f2b(w0[0]); bb[1] = f2b(w0[1]);                       \
              bb[2] = f2b(w0[2]); bb[3] = f2b(w0[3]);                       \
              bb[4] = f2b(w1[0]); bb[5] = f2b(w1[1]);                       \
              bb[6] = f2b(w1[2]); bb[7] = f2b(w1[3]);                       \
              _Pragma("unroll")                                             \
              for (int tg = 0; tg < 4; ++tg)                                \
                  acc[tg] = __builtin_amdgcn_mfma_f32_16x16x32_bf16(        \
                      XF[tg][s], bb, acc[tg], 0, 0, 0);                     \
          } }

    LOADX(XA, 0);
    for (int t = 0; t < 32; t += 2) {
        LOADX(XB, t + 1);                    // issued before tile-t waits
        COMPT(XA, t);
        if (t + 2 < 32) LOADX(XA, t + 2);    // issued before tile-t+1 waits
        COMPT(XB, t + 1);
    }

    #undef LOADX
    #undef COMPT

    // lora tail: 2 K-steps over r=64 with B matrix and y2
    {
        const float* br = Bm + (size_t)(j0 + c) * 64 + kg * 8;
        #pragma unroll
        for (int k = 0; k < 64; k += 32) {
            f32x4 w0 = *(const f32x4*)(br + k);
            f32x4 w1 = *(const f32x4*)(br + k + 4);
            bf16x8 bb;
            bb[0] = f2b(w0[0]); bb[1] = f2b(w0[1]);
            bb[2] = f2b(w0[2]); bb[3] = f2b(w0[3]);
            bb[4] = f2b(w1[0]); bb[5] = f2b(w1[1]);
            bb[6] = f2b(w1[2]); bb[7] = f2b(w1[3]);
            #pragma unroll
            for (int tg = 0; tg < 4; ++tg) {
                bf16x8 aa = *(const bf16x8*)(yb + (size_t)(tg * 16 + c) * 64
                                             + kg * 8 + k);
                acc[tg] = __builtin_amdgcn_mfma_f32_16x16x32_bf16(
                    aa, bb, acc[tg], 0, 0, 0);
            }
        }
    }

    // store: token row = tg*16 + kg*4 + r, col = j0 + c
    float* op = out + j0 + c;
    #pragma unroll
    for (int tg = 0; tg < 4; ++tg)
        #pragma unroll
        for (int r = 0; r < 4; ++r)
            op[(size_t)(tg * 16 + kg * 4 + r) * 16384] = acc[tg][r];
}

extern "C" void kernel_launch(void* const* d_in, const int* in_sizes, int n_in,
                              void* d_out, int out_size, void* d_ws, size_t ws_size,
                              hipStream_t stream) {
    const float* x  = (const float*)d_in[0];
    const float* W  = (const float*)d_in[1];
    const float* A  = (const float*)d_in[2];
    const float* Bm = (const float*)d_in[3];
    float* out = (float*)d_out;

    ushort* xb = (ushort*)d_ws;                          // 64*4096*2 = 524288 B
    ushort* yb = (ushort*)((char*)d_ws + 524288);        // 64*64*2   = 8192 B

    prep_kernel<<<1024, 256, 0, stream>>>(x, A, xb, yb);
    lora_gemm<<<1024, 64, 0, stream>>>(W, Bm, xb, yb, out);
}

// Round 9
// 98.546 us; speedup vs baseline: 1.5259x; 1.2776x over previous
//
#include <hip/hip_runtime.h>
#include <hip/hip_bf16.h>

typedef __attribute__((ext_vector_type(8))) short bf16x8;
typedef __attribute__((ext_vector_type(4))) short s16x4;
typedef __attribute__((ext_vector_type(4))) float f32x4;

__device__ __forceinline__ short f2b(float f) {
    __hip_bfloat16 h = __float2bfloat16(f);   // RNE
    return __builtin_bit_cast(short, h);
}

#define KT 512      // K-tile in floats (2 KB/row f32, 1 KB/row bf16 in LDS)
#define NT 8        // 4096 / 512

// Kernel 1: x f32 -> bf16, and y2 = 2*(x @ A^T) as bf16.
__global__ void prep_kernel(const float* __restrict__ x,
                            const float* __restrict__ A,
                            ushort* __restrict__ xb,     // [64][4096] bf16
                            ushort* __restrict__ yb) {   // [64][64] bf16
    const int tid = threadIdx.x, bid = blockIdx.x;

    const int gid = bid * 256 + tid;
    if (gid < 65536) {
        float4 v = ((const float4*)x)[gid];
        ushort4 s;
        s.x = (ushort)f2b(v.x); s.y = (ushort)f2b(v.y);
        s.z = (ushort)f2b(v.z); s.w = (ushort)f2b(v.w);
        ((ushort4*)xb)[gid] = s;
    }

    const int wave = tid >> 6, lane = tid & 63;
    const int idx = bid * 4 + wave;          // 0..4095
    const int t = idx >> 6, r = idx & 63;
    const float4* xr = (const float4*)(x + (size_t)t * 4096);
    const float4* ar = (const float4*)(A + (size_t)r * 4096);
    float s = 0.f;
    #pragma unroll
    for (int i = 0; i < 16; ++i) {
        float4 a = xr[i * 64 + lane];
        float4 b = ar[i * 64 + lane];
        s += a.x * b.x + a.y * b.y + a.z * b.z + a.w * b.w;
    }
    #pragma unroll
    for (int off = 32; off; off >>= 1) s += __shfl_xor(s, off, 64);
    if (lane == 0) yb[idx] = (ushort)f2b(2.0f * s);
}

// Kernel 2: out[64][16384] = x@W^T + y2@B^T.  (R5 structure, byte-identical
// schedule; ONE change: W and Bm loads are NON-TEMPORAL.)
// Rationale: W is 256 MiB = exactly L3 size, read exactly once per launch ->
// zero in-kernel reuse, but every line pays L3 insert+evict churn. FETCH_SIZE
// showed only ~half of W comes from HBM (L3 residue from the previous
// replay) yet delivered BW is stuck at 3.2 TB/s across ALL structures --
// suspected L3 miss/fill throughput wall. nt flag streams W past the cache.
__global__ void __launch_bounds__(256)
lora_gemm(const float* __restrict__ W,      // [16384][4096]
          const float* __restrict__ Bm,     // [16384][64]
          const ushort* __restrict__ xb,    // [64][4096] bf16
          const ushort* __restrict__ yb,    // [64][64] bf16
          float* __restrict__ out) {        // [64][16384]
    __shared__ ushort lds[2][16 * KT];      // 2 x 16 KB (bf16)

    const int tid  = threadIdx.x;
    const int w    = tid >> 6;              // wave 0..3 -> token group
    const int lane = tid & 63;
    const int c    = lane & 15;             // frag row/col index
    const int kg   = lane >> 4;             // k-group, offset kg*8
    const int j0   = blockIdx.x << 4;
    const int sx   = (c & 7) << 4;          // read-side swizzle

    const ushort* xrow = xb + (size_t)(w * 16 + c) * 4096 + kg * 8;

    f32x4 rg[4][2];                          // staged W: 4 rows x 2 chunks

    // wave w loads rows w*4..w*4+3; per row 2 chunks of 1 KB, lane-linear.
    auto load_tile = [&](int t) {
        #pragma unroll
        for (int q = 0; q < 4; ++q) {
            const float* src = W + (size_t)(j0 + w * 4 + q) * 4096
                                 + (size_t)t * KT + lane * 4;
            rg[q][0] = __builtin_nontemporal_load((const f32x4*)src);
            rg[q][1] = __builtin_nontemporal_load((const f32x4*)(src + 256));
        }
    };
    // convert to bf16 and write XOR-swizzled (write-side swizzle is legal
    // with reg-staging; matches the read-side XOR below).
    auto write_tile = [&](int buf) {
        #pragma unroll
        for (int q = 0; q < 4; ++q) {
            const int r = w * 4 + q;
            char* rowb = (char*)&lds[buf][0] + r * 1024;
            #pragma unroll
            for (int h = 0; h < 2; ++h) {
                s16x4 p;
                p[0] = f2b(rg[q][h][0]); p[1] = f2b(rg[q][h][1]);
                p[2] = f2b(rg[q][h][2]); p[3] = f2b(rg[q][h][3]);
                *(s16x4*)(rowb + ((h * 512 + lane * 8) ^ ((r & 7) << 4))) = p;
            }
        }
    };

    f32x4 acc = {0.f, 0.f, 0.f, 0.f};

    load_tile(0);
    write_tile(0);
    __syncthreads();

    for (int t = 0; t < NT; ++t) {
        const int cur = t & 1;
        if (t + 1 < NT) load_tile(t + 1);    // in flight under MFMA phase

        const char* lrow = (const char*)&lds[cur][0] + c * 1024;
        #pragma unroll
        for (int s = 0; s < 16; ++s) {
            bf16x8 bb = *(const bf16x8*)(lrow + ((s * 64 + kg * 16) ^ sx));
            bf16x8 aa = *(const bf16x8*)(xrow + (size_t)t * KT + s * 32);
            acc = __builtin_amdgcn_mfma_f32_16x16x32_bf16(aa, bb, acc, 0, 0, 0);
        }

        if (t + 1 < NT) {
            write_tile(cur ^ 1);             // other buffer; last read at t-1,
            __syncthreads();                 // protected by t-1's barrier
        }
    }

    // lora tail: 2 K-steps over r=64 with B matrix and y2
    {
        const float*  br = Bm + (size_t)(j0 + c) * 64 + kg * 8;
        const ushort* y0 = yb + (size_t)(w * 16 + c) * 64 + kg * 8;
        #pragma unroll
        for (int k = 0; k < 64; k += 32) {
            f32x4 w0 = __builtin_nontemporal_load((const f32x4*)(br + k));
            f32x4 w1 = __builtin_nontemporal_load((const f32x4*)(br + k + 4));
            bf16x8 bb;
            bb[0] = f2b(w0[0]); bb[1] = f2b(w0[1]);
            bb[2] = f2b(w0[2]); bb[3] = f2b(w0[3]);
            bb[4] = f2b(w1[0]); bb[5] = f2b(w1[1]);
            bb[6] = f2b(w1[2]); bb[7] = f2b(w1[3]);
            bf16x8 aa = *(const bf16x8*)(y0 + k);
            acc = __builtin_amdgcn_mfma_f32_16x16x32_bf16(aa, bb, acc, 0, 0, 0);
        }
    }

    // store: token row = w*16 + kg*4 + r, col = j0 + c
    float* op = out + j0 + c;
    #pragma unroll
    for (int r = 0; r < 4; ++r)
        op[(size_t)(w * 16 + kg * 4 + r) * 16384] = acc[r];
}

extern "C" void kernel_launch(void* const* d_in, const int* in_sizes, int n_in,
                              void* d_out, int out_size, void* d_ws, size_t ws_size,
                              hipStream_t stream) {
    const float* x  = (const float*)d_in[0];
    const float* W  = (const float*)d_in[1];
    const float* A  = (const float*)d_in[2];
    const float* Bm = (const float*)d_in[3];
    float* out = (float*)d_out;

    ushort* xb = (ushort*)d_ws;                          // 64*4096*2 = 524288 B
    ushort* yb = (ushort*)((char*)d_ws + 524288);        // 64*64*2   = 8192 B

    prep_kernel<<<1024, 256, 0, stream>>>(x, A, xb, yb);
    lora_gemm<<<1024, 256, 0, stream>>>(W, Bm, xb, yb, out);
}